// Round 4
// baseline (141.012 us; speedup 1.0000x reference)
//
#include <hip/hip_runtime.h>

#define NBINS 64
#define HB (2 * NBINS)              // 128 bins total (sim + dis)
#define HIST_BLOCKS 512
#define HIST_THREADS 512            // 8 waves/block
#define WAVES_PER_BLOCK (HIST_THREADS / 64)
// Harness re-poisons d_ws to 0xAA before EVERY launch, so a uint32 counter in
// ws deterministically starts at 0xAAAAAAAA. If this contract ever breaks,
// out[0] is never written and the absmax check fails loudly (no hang: no
// block ever spin-waits).
#define POISON_BASE 0xAAAAAAAAu

__device__ __forceinline__ void accum_point(float x, float* h) {
    // clip to [-1,1]; u = (x+1)/LAM with 1/LAM = (R-1)/2 = 31.5 exactly
    float s = fminf(fmaxf(x, -1.0f), 1.0f);
    float u = (s + 1.0f) * 31.5f;          // in [0, 63]
    int   b = (int)u;                      // floor (u >= 0)
    float f = u - (float)b;                // frac
    // f==0 (exact bin center, incl. x=+-1) contributes 0 in the reference
    // (strict inequalities); guard also keeps b+1 <= 63.
    if (f > 0.0f) {
        atomicAdd(&h[b],     1.0f - f);
        atomicAdd(&h[b + 1], f);
    }
}

__global__ __launch_bounds__(HIST_THREADS) void fused_kernel(
        const float* __restrict__ sim,
        const float* __restrict__ dis,
        float* __restrict__ partials,      // [HIST_BLOCKS][HB] in ws
        unsigned int* __restrict__ counter,// in ws, poison-initialized
        float* __restrict__ out,
        int n, float invN) {
    __shared__ float h[WAVES_PER_BLOCK * HB];   // 4 KB; reused as red[] later
    __shared__ float tot[HB];
    __shared__ unsigned int is_last;

    for (int i = threadIdx.x; i < WAVES_PER_BLOCK * HB; i += blockDim.x)
        h[i] = 0.0f;
    __syncthreads();

    // ---- phase 1: per-wave soft histograms (no inter-wave contention) ----
    float* hw = &h[(threadIdx.x >> 6) * HB];
    int tid = blockIdx.x * blockDim.x + threadIdx.x;
    int nthreads = gridDim.x * blockDim.x;      // 262144 == n/4 exactly
    int nvec = n >> 2;
    const float4* sim4 = (const float4*)sim;
    const float4* dis4 = (const float4*)dis;

    for (int i = tid; i < nvec; i += nthreads) {
        float4 s4 = sim4[i];
        float4 d4 = dis4[i];
        accum_point(s4.x, hw);
        accum_point(s4.y, hw);
        accum_point(s4.z, hw);
        accum_point(s4.w, hw);
        accum_point(d4.x, hw + NBINS);
        accum_point(d4.y, hw + NBINS);
        accum_point(d4.z, hw + NBINS);
        accum_point(d4.w, hw + NBINS);
    }
    for (int i = (nvec << 2) + tid; i < n; i += nthreads) {
        accum_point(sim[i], hw);
        accum_point(dis[i], hw + NBINS);
    }
    __syncthreads();

    // fold wave-copies -> per-block partial (coalesced stores, no atomics)
    if (threadIdx.x < HB) {
        int j = threadIdx.x;
        float v = 0.0f;
        #pragma unroll
        for (int w = 0; w < WAVES_PER_BLOCK; ++w) v += h[w * HB + j];
        partials[blockIdx.x * HB + j] = v;
    }

    // ---- completion protocol: release partials, bump device-scope counter ----
    __threadfence();                            // release: wb past XCD L2
    if (threadIdx.x == 0) {
        unsigned int old = atomicAdd(counter, 1u);
        is_last = (old == POISON_BASE + (unsigned)gridDim.x - 1u) ? 1u : 0u;
    }
    __syncthreads();                            // also: all fold-reads of h done
    if (!is_last) return;

    // ---- phase 2 (last block only): reduce + cumsum + dots ----
    __threadfence();                            // acquire: invalidate caches

    int t = threadIdx.x;
    int j = t & (HB - 1);
    int seg = t >> 7;                           // 4 segments x 128 bins
    const int rows = HIST_BLOCKS / 4;           // 128 block-rows per segment
    float s = 0.0f;
    int base = seg * rows;
    for (int k = 0; k < rows; ++k)
        s += partials[(base + k) * HB + j];     // lane-coalesced over j
    h[seg * HB + j] = s;                        // reuse h (reads finished above)
    __syncthreads();

    if (t < HB)
        tot[t] = h[t] + h[HB + t] + h[2 * HB + t] + h[3 * HB + t];
    __syncthreads();

    if (t < 64) {
        int lane = t;
        float hp = tot[lane] * invN;
        float hm = tot[NBINS + lane] * invN;

        // inclusive 64-lane prefix sum (cumsum)
        float hpc = hp, hmc = hm;
        #pragma unroll
        for (int off = 1; off < 64; off <<= 1) {
            float a = __shfl_up(hpc, off, 64);
            float b = __shfl_up(hmc, off, 64);
            if (lane >= off) { hpc += a; hmc += b; }
        }

        const float q = 0.9f, p = 0.1f;
        float v = q * q * hpc * hm
                - q * p * hpc * hp
                - q * p * hmc * hm
                + p * p * hmc * hp;

        #pragma unroll
        for (int off = 32; off >= 1; off >>= 1) v += __shfl_down(v, off, 64);

        if (lane == 0) out[0] = v / 0.64f;      // (1-2P)^2 = 0.64
    }
}

extern "C" void kernel_launch(void* const* d_in, const int* in_sizes, int n_in,
                              void* d_out, int out_size, void* d_ws, size_t ws_size,
                              hipStream_t stream) {
    const float* sim = (const float*)d_in[0];
    const float* dis = (const float*)d_in[1];
    int n = in_sizes[0];
    float* partials = (float*)d_ws;                          // 256 KB, fully overwritten
    unsigned int* counter = (unsigned int*)((char*)d_ws + HIST_BLOCKS * HB * sizeof(float));

    fused_kernel<<<HIST_BLOCKS, HIST_THREADS, 0, stream>>>(
        sim, dis, partials, counter, (float*)d_out, n, 1.0f / (float)n);
}

// Round 5
// 73.447 us; speedup vs baseline: 1.9199x; 1.9199x over previous
//
#include <hip/hip_runtime.h>

#define NBINS 64
#define HB (2 * NBINS)              // 128 bins total (sim + dis)
#define HIST_BLOCKS 1024
#define HIST_THREADS 256            // 4 waves/block -> 16 waves/CU at 4 blocks/CU
#define WPB (HIST_THREADS / 64)
#define SEGS 8
#define INV_SCALE (1.0f / 65536.0f)

// Fixed-point LDS histogram: ds_add_u32 is always a native LDS atomic (no CAS
// loop, unlike float atomicAdd under IEEE denormal mode). Each point deposits
// exactly 65536 split between bins b and b+1, so mass is conserved exactly.
__device__ __forceinline__ void accum_point(float x, unsigned* h) {
    float s = fminf(fmaxf(x, -1.0f), 1.0f);
    float u = (s + 1.0f) * 31.5f;          // 1/LAM = (R-1)/2 = 31.5 exact
    int   b = (int)u;                      // floor, 0..63
    float f = u - (float)b;
    // f==0 (exact bin center, incl. x=+-1) contributes 0 in the reference
    // (strict inequalities); guard also implies b <= 62 when we do add.
    if (f > 0.0f) {
        unsigned wf = (unsigned)(f * 65536.0f + 0.5f);   // round-to-nearest
        atomicAdd(&h[b],     65536u - wf);
        atomicAdd(&h[b + 1], wf);
    }
}

__global__ __launch_bounds__(HIST_THREADS) void hist_kernel(
        const float* __restrict__ sim,
        const float* __restrict__ dis,
        float* __restrict__ partials,   // [HIST_BLOCKS][HB]
        int n) {
    __shared__ unsigned h[WPB * HB];    // per-wave sub-hists, 2 KB
    for (int i = threadIdx.x; i < WPB * HB; i += blockDim.x) h[i] = 0u;
    __syncthreads();

    unsigned* hw = &h[(threadIdx.x >> 6) * HB];

    int tid = blockIdx.x * blockDim.x + threadIdx.x;
    int nthreads = gridDim.x * blockDim.x;   // 262144 == n/4 exactly
    int nvec = n >> 2;
    const float4* sim4 = (const float4*)sim;
    const float4* dis4 = (const float4*)dis;

    for (int i = tid; i < nvec; i += nthreads) {
        float4 s4 = sim4[i];
        float4 d4 = dis4[i];
        accum_point(s4.x, hw);
        accum_point(s4.y, hw);
        accum_point(s4.z, hw);
        accum_point(s4.w, hw);
        accum_point(d4.x, hw + NBINS);
        accum_point(d4.y, hw + NBINS);
        accum_point(d4.z, hw + NBINS);
        accum_point(d4.w, hw + NBINS);
    }
    for (int i = (nvec << 2) + tid; i < n; i += nthreads) {
        accum_point(sim[i], hw);
        accum_point(dis[i], hw + NBINS);
    }
    __syncthreads();

    // fold wave copies (u32, max ~2^27) -> float partial, coalesced store
    if (threadIdx.x < HB) {
        int j = threadIdx.x;
        unsigned v = 0u;
        #pragma unroll
        for (int w = 0; w < WPB; ++w) v += h[w * HB + j];
        partials[blockIdx.x * HB + j] = (float)v * INV_SCALE;
    }
}

__global__ __launch_bounds__(1024) void final_kernel(
        const float* __restrict__ partials,   // [HIST_BLOCKS][HB]
        float* __restrict__ out, float invN) {
    __shared__ float red[SEGS * HB];
    __shared__ float tot[HB];

    int t = threadIdx.x;
    int j = t & (HB - 1);
    int seg = t >> 7;                          // 8 segments x 128 bins
    const int rows = HIST_BLOCKS / SEGS;       // 128 block-rows per segment
    float s = 0.0f;
    int base = seg * rows;
    #pragma unroll 8
    for (int k = 0; k < rows; ++k)
        s += partials[(base + k) * HB + j];    // lane-coalesced over j
    red[seg * HB + j] = s;
    __syncthreads();

    if (t < HB) {
        float v = 0.0f;
        #pragma unroll
        for (int g = 0; g < SEGS; ++g) v += red[g * HB + t];
        tot[t] = v;
    }
    __syncthreads();

    if (t < 64) {
        int lane = t;
        float hp = tot[lane] * invN;
        float hm = tot[NBINS + lane] * invN;

        // inclusive 64-lane prefix sum (cumsum)
        float hpc = hp, hmc = hm;
        #pragma unroll
        for (int off = 1; off < 64; off <<= 1) {
            float a = __shfl_up(hpc, off, 64);
            float b = __shfl_up(hmc, off, 64);
            if (lane >= off) { hpc += a; hmc += b; }
        }

        const float q = 0.9f, p = 0.1f;
        float v = q * q * hpc * hm
                - q * p * hpc * hp
                - q * p * hmc * hm
                + p * p * hmc * hp;

        #pragma unroll
        for (int off = 32; off >= 1; off >>= 1) v += __shfl_down(v, off, 64);

        if (lane == 0) out[0] = v / 0.64f;     // (1-2P)^2 = 0.64
    }
}

extern "C" void kernel_launch(void* const* d_in, const int* in_sizes, int n_in,
                              void* d_out, int out_size, void* d_ws, size_t ws_size,
                              hipStream_t stream) {
    const float* sim = (const float*)d_in[0];
    const float* dis = (const float*)d_in[1];
    int n = in_sizes[0];
    float* partials = (float*)d_ws;   // 1024*128 floats = 512 KB, fully overwritten

    hist_kernel<<<HIST_BLOCKS, HIST_THREADS, 0, stream>>>(sim, dis, partials, n);
    final_kernel<<<1, 1024, 0, stream>>>(partials, (float*)d_out, 1.0f / (float)n);
}